// Round 6
// baseline (388.474 us; speedup 1.0000x reference)
//
#include <hip/hip_runtime.h>
#include <stdint.h>

#define HD   256
#define SEQ  4096
#define NB   4
#define NROW (NB * SEQ)   // 16384

typedef __attribute__((ext_vector_type(8))) short short8;
typedef __attribute__((ext_vector_type(4))) float f32x4;
typedef __attribute__((ext_vector_type(16))) float f32x16;
typedef _Float16 v8h __attribute__((ext_vector_type(8)));

__device__ __forceinline__ unsigned short f2bf(float f) {
  union { float f; unsigned u; } v; v.f = f;
  unsigned u = v.u;
  u += 0x7fffu + ((u >> 16) & 1u);
  return (unsigned short)(u >> 16);
}
__device__ __forceinline__ float bf2f(unsigned short h) {
  union { float f; unsigned u; } v; v.u = ((unsigned)h) << 16;
  return v.f;
}
__device__ __forceinline__ unsigned short f2h(float f) {
  union { _Float16 h; unsigned short u; } v;
  v.h = (_Float16)f;
  return v.u;
}
__device__ __forceinline__ float h2f(unsigned short u) {
  union { _Float16 h; unsigned short u; } v;
  v.u = u;
  return (float)v.h;
}

__device__ __forceinline__ f32x4 mfma16(short8 a, short8 b, f32x4 c) {
  return __builtin_amdgcn_mfma_f32_16x16x32_bf16(a, b, c, 0, 0, 0);
}
__device__ __forceinline__ f32x16 mfma32h(v8h a, v8h b, f32x16 c) {
  return __builtin_amdgcn_mfma_f32_32x32x16_f16(a, b, c, 0, 0, 0);
}

__device__ __forceinline__ void gload_lds16(const void* g, void* l) {
  __builtin_amdgcn_global_load_lds((const __attribute__((address_space(1))) void*)g,
                                   (__attribute__((address_space(3))) void*)l,
                                   16, 0, 0);
}

// ---------------------------------------------------------------------------
// Kernel 0: split x (f32) into bf16 hi/lo once.
// ---------------------------------------------------------------------------
__global__ __launch_bounds__(256) void prep_x_kernel(
    const float* __restrict__ x,
    unsigned short* __restrict__ xh, unsigned short* __restrict__ xl)
{
  int i = blockIdx.x * 256 + threadIdx.x;      // 8 elems per thread
  const float* p = x + i * 8;
  f32x4 a0 = *(const f32x4*)p;
  f32x4 a1 = *(const f32x4*)(p + 4);
  short8 hh, ll;
#pragma unroll
  for (int j = 0; j < 4; ++j) {
    unsigned short h0 = f2bf(a0[j]);
    hh[j]     = (short)h0;
    ll[j]     = (short)f2bf(a0[j] - bf2f(h0));
    unsigned short h1 = f2bf(a1[j]);
    hh[4 + j] = (short)h1;
    ll[4 + j] = (short)f2bf(a1[j] - bf2f(h1));
  }
  *(short8*)(xh + i * 8) = hh;
  *(short8*)(xl + i * 8) = ll;
}

// ---------------------------------------------------------------------------
// Kernel 1: transpose + hi/lo split the weight matrices (bf16).
// ---------------------------------------------------------------------------
__global__ __launch_bounds__(256) void prep_w_kernel(
    const float* __restrict__ Wq, const float* __restrict__ Wk,
    const float* __restrict__ Wv,
    unsigned short* __restrict__ WTh, unsigned short* __restrict__ WTl)
{
  int flat = blockIdx.x * 256 + threadIdx.x;   // 0 .. 3*65536-1
  int mat = flat >> 16;
  int e   = flat & 65535;
  int o   = e >> 8;
  int k   = e & 255;
  const float* W = (mat == 0) ? Wq : (mat == 1) ? Wk : Wv;
  float v = W[k * 256 + o];
  unsigned short h = f2bf(v);
  WTh[flat] = h;
  WTl[flat] = f2bf(v - bf2f(h));
}

// ---------------------------------------------------------------------------
// Kernel 2: QKV projection via split-bf16 3-product MFMA; outputs fp16.
// mat 0 -> Qf [row][h], 1 -> Kf [row][h], 2 -> VT [b][h][s] (transposed).
// ---------------------------------------------------------------------------
__global__ __launch_bounds__(256) void proj_kernel(
    const unsigned short* __restrict__ xh, const unsigned short* __restrict__ xl,
    const unsigned short* __restrict__ WTh, const unsigned short* __restrict__ WTl,
    const float* __restrict__ bq, const float* __restrict__ bk,
    const float* __restrict__ bv,
    unsigned short* __restrict__ Qf, unsigned short* __restrict__ Kf,
    unsigned short* __restrict__ VT)
{
  const int mat = blockIdx.y;
  const int r0  = blockIdx.x << 6;     // 64-row tile
  const int tid = threadIdx.x;
  const int w    = tid >> 6;
  const int lane = tid & 63;
  const int lr   = lane & 15;
  const int hi4  = lane >> 4;
  const int r4   = hi4 << 2;

  const unsigned short* wth = WTh + (mat << 16);
  const unsigned short* wtl = WTl + (mat << 16);

  f32x4 acc[4][4] = {};

#pragma unroll
  for (int ks = 0; ks < 8; ++ks) {
    short8 ah[4], al[4];
#pragma unroll
    for (int m = 0; m < 4; ++m) {
      int off = (r0 + (m << 4) + lr) * 256 + (ks << 5) + (hi4 << 3);
      ah[m] = *(const short8*)(xh + off);
      al[m] = *(const short8*)(xl + off);
    }
#pragma unroll
    for (int n = 0; n < 4; ++n) {
      int o = (w << 6) + (n << 4) + lr;
      short8 bh = *(const short8*)(wth + o * 256 + (ks << 5) + (hi4 << 3));
      short8 bl = *(const short8*)(wtl + o * 256 + (ks << 5) + (hi4 << 3));
#pragma unroll
      for (int m = 0; m < 4; ++m) acc[m][n] = mfma16(ah[m], bh, acc[m][n]);
#pragma unroll
      for (int m = 0; m < 4; ++m) acc[m][n] = mfma16(al[m], bh, acc[m][n]);
#pragma unroll
      for (int m = 0; m < 4; ++m) acc[m][n] = mfma16(ah[m], bl, acc[m][n]);
    }
  }

  const float* bias = (mat == 0) ? bq : (mat == 1) ? bk : bv;
#pragma unroll
  for (int n = 0; n < 4; ++n) {
    int col = (w << 6) + (n << 4) + lr;
    float bb = bias[col];
#pragma unroll
    for (int m = 0; m < 4; ++m) {
#pragma unroll
      for (int reg = 0; reg < 4; ++reg) {
        int row = r0 + (m << 4) + r4 + reg;     // global row in [0,16384)
        float val = acc[m][n][reg] + bb;
        unsigned short h = f2h(val);
        if (mat == 0) {
          Qf[row * 256 + col] = h;
        } else if (mat == 1) {
          Kf[row * 256 + col] = h;
        } else {
          int b = row >> 12, s = row & 4095;
          VT[(b << 20) + (col << 12) + s] = h;
        }
      }
    }
  }
}

// ---------------------------------------------------------------------------
// Kernel 3: causal flash attention, 32x32x16 MFMA, BQ=128 (4 waves x 32 rows).
// 256 blocks = (batch, pair p, chunk s). Pair {jA=p, jB=31-p} has exactly
// 66 k-tiles total; chunk s takes global positions [33s/2, 33(s+1)/2) of the
// concatenated [A-range | B-range] -> 16-17 tiles per block, perfect balance.
// Double-buffered K/V staging (144 KB LDS, 1 block/CU), full XOR swizzles,
// l accumulated via MFMA-with-ones, defer-max THR=8, mask = -3e38.
// Partials: O/l normalized fp16 + (m, l) f32 per slot; merge combines 4 slots.
// ---------------------------------------------------------------------------
__global__ __launch_bounds__(256, 1) void attn_kernel(
    const unsigned short* __restrict__ Qf, const unsigned short* __restrict__ Kf,
    const unsigned short* __restrict__ VT,
    unsigned short* __restrict__ Opart, float* __restrict__ Mpart,
    float* __restrict__ Lpart)
{
  __shared__ __align__(16) unsigned short sK[2][64 * 256];
  __shared__ __align__(16) unsigned short sV[2][256 * 64];
  __shared__ __align__(16) unsigned short sP[4][32 * 64];

  const int bx    = blockIdx.x;
  const int xcd   = bx & 7;
  const int batch = xcd >> 1;
  const int e     = xcd & 1;
  const int rnk   = bx >> 3;                 // 0..31
  const int p     = rnk & 15;
  const int s     = (rnk >> 4) | (e << 1);   // 0..3
  const int jA = p, jB = 31 - p;
  const int LA = 2 * p + 2;                  // tiles in segment A
  const int g0 = (33 * s) >> 1;              // 0,16,33,49
  const int g1 = (33 * (s + 1)) >> 1;        // 16,33,49,66

  const int tid  = threadIdx.x;
  const int w    = tid >> 6;
  const int lane = tid & 63;
  const int lc   = lane & 31;
  const int hi   = lane >> 5;

  const unsigned short* Kf_b = Kf + (batch << 20);
  const unsigned short* VT_b = VT + (batch << 20);

  auto stage = [&](int buf, int kt) {
#pragma unroll
    for (int it = 0; it < 8; ++it) {
      int id = it * 256 + tid;
      int kr = id >> 5, cb = id & 31;
      gload_lds16(Kf_b + (((kt << 6) + kr) << 8) + (((cb ^ kr) & 31) << 3),
                  &sK[buf][id * 8]);
      int hd = id >> 3, cb2 = id & 7;
      gload_lds16(VT_b + (hd << 12) + (kt << 6) + (((cb2 ^ (hd >> 2)) & 7) << 3),
                  &sV[buf][id * 8]);
    }
  };

  v8h qf[16];
  auto loadQ = [&](int j) {
    const unsigned short* qp =
        Qf + (size_t)(((batch << 5) + j) * 128 + (w << 5) + lc) * 256 + (hi << 3);
#pragma unroll
    for (int ks = 0; ks < 16; ++ks)
      qf[ks] = *(const v8h*)(qp + (ks << 4));
  };

  float m_[16];
  f32x16 accl;
  f32x16 oacc[8];
  auto resetAcc = [&]() {
#pragma unroll
    for (int r = 0; r < 16; ++r) { m_[r] = -1e30f; accl[r] = 0.f; }
#pragma unroll
    for (int n = 0; n < 8; ++n)
#pragma unroll
      for (int r = 0; r < 16; ++r) oacc[n][r] = 0.f;
  };

  auto flush = [&](int j) {
    int slot = (((batch << 5) + j) << 2) + s;
    unsigned short* Op = Opart + (size_t)slot * (128 * 256);
    float invl[16];
#pragma unroll
    for (int r = 0; r < 16; ++r)
      invl[r] = (accl[r] > 0.f) ? (1.0f / accl[r]) : 0.f;
#pragma unroll
    for (int n = 0; n < 8; ++n) {
#pragma unroll
      for (int r = 0; r < 16; ++r) {
        int row = (w << 5) + (r & 3) + ((r >> 2) << 3) + (hi << 2);
        Op[row * 256 + (n << 5) + lc] = f2h(oacc[n][r] * invl[r]);
      }
    }
    if (lc == 0) {
#pragma unroll
      for (int r = 0; r < 16; ++r) {
        int row = (w << 5) + (r & 3) + ((r >> 2) << 3) + (hi << 2);
        Mpart[slot * 128 + row] = m_[r];
        Lpart[slot * 128 + row] = accl[r];
      }
    }
  };
  auto writeEmpty = [&](int j) {
    int slot = (((batch << 5) + j) << 2) + s;
    if (lc == 0) {
#pragma unroll
      for (int r = 0; r < 16; ++r) {
        int row = (w << 5) + (r & 3) + ((r >> 2) << 3) + (hi << 2);
        Mpart[slot * 128 + row] = -1e30f;
        Lpart[slot * 128 + row] = 0.f;
      }
    }
  };

  const int aEnd   = (g1 < LA) ? g1 : LA;
  const bool hasA  = g0 < aEnd;
  const int bStart = (g0 > LA) ? g0 : LA;
  const bool hasB  = bStart < g1;

  resetAcc();
  int curj = hasA ? jA : jB;
  loadQ(curj);

  {
    int kt0 = (g0 < LA) ? g0 : (g0 - LA);
    stage(0, kt0);
  }
  __syncthreads();
  int cur = 0;

  const v8h vone = {(_Float16)1.f, (_Float16)1.f, (_Float16)1.f, (_Float16)1.f,
                    (_Float16)1.f, (_Float16)1.f, (_Float16)1.f, (_Float16)1.f};

  for (int g = g0; g < g1; ++g) {
    const bool inA = g < LA;
    const int j  = inA ? jA : jB;
    const int kt = inA ? g : (g - LA);

    if (j != curj) {           // crossed A->B boundary
      flush(jA);
      resetAcc();
      loadQ(jB);
      curj = jB;
    }

    if (g + 1 < g1) {
      int gn = g + 1;
      int ktn = (gn < LA) ? gn : (gn - LA);
      stage(cur ^ 1, ktn);
    }

    const unsigned short* sKc = sK[cur];
    const unsigned short* sVc = sV[cur];

    // ---- QK^T: S[32q][64k], two 32-key column tiles
    f32x16 sacc0, sacc1;
#pragma unroll
    for (int r = 0; r < 16; ++r) { sacc0[r] = 0.f; sacc1[r] = 0.f; }
    __builtin_amdgcn_s_setprio(1);
#pragma unroll
    for (int ks = 0; ks < 16; ++ks) {
      int c = (ks << 1) + hi;                           // 16B chunk in K row
      v8h kb0 = *(const v8h*)(sKc + (lc << 8) + (((c ^ lc) & 31) << 3));
      v8h kb1 = *(const v8h*)(sKc + ((32 + lc) << 8) + (((c ^ lc) & 31) << 3));
      sacc0 = mfma32h(qf[ks], kb0, sacc0);
      sacc1 = mfma32h(qf[ks], kb1, sacc1);
    }
    __builtin_amdgcn_s_setprio(0);

    // ---- causal mask (element-wise on diagonal-crossing tiles)
    const int q0 = j << 7;
    if ((kt << 6) + 63 > q0 + (w << 5)) {
#pragma unroll
      for (int r = 0; r < 16; ++r) {
        int qg = q0 + (w << 5) + (r & 3) + ((r >> 2) << 3) + (hi << 2);
        int kg = (kt << 6) + lc;
        if (kg > qg)      sacc0[r] = -3e38f;
        if (kg + 32 > qg) sacc1[r] = -3e38f;
      }
    }

    // ---- row max (reduce over 32 lanes within each half)
    float mx[16];
#pragma unroll
    for (int r = 0; r < 16; ++r) mx[r] = fmaxf(sacc0[r], sacc1[r]);
#pragma unroll
    for (int d = 1; d < 32; d <<= 1) {
#pragma unroll
      for (int r = 0; r < 16; ++r)
        mx[r] = fmaxf(mx[r], __shfl_xor(mx[r], d, 64));
    }

    // ---- defer-max: rescale only when max grows by > 8
    bool need = false;
#pragma unroll
    for (int r = 0; r < 16; ++r) need = need || (mx[r] > m_[r] + 8.0f);
    if (__any(need)) {
#pragma unroll
      for (int r = 0; r < 16; ++r) {
        float mn = fmaxf(m_[r], mx[r]);
        float sc = __expf(m_[r] - mn);
        m_[r] = mn;
        accl[r] *= sc;
#pragma unroll
        for (int n = 0; n < 8; ++n) oacc[n][r] *= sc;
      }
    }

    // ---- P = exp(S - m) -> fp16 -> per-wave swizzled LDS
    unsigned short* pw = (unsigned short*)sP[w];
#pragma unroll
    for (int r = 0; r < 16; ++r) {
      int row = (r & 3) + ((r >> 2) << 3) + (hi << 2);
      int swz = (row >> 2) & 7;
      float p0 = __expf(sacc0[r] - m_[r]);
      float p1 = __expf(sacc1[r] - m_[r]);
      pw[row * 64 + ((((lc >> 3) ^ swz) << 3) | (lc & 7))]        = f2h(p0);
      pw[row * 64 + (((((lc + 32) >> 3) ^ swz) << 3) | (lc & 7))] = f2h(p1);
    }

    // ---- P A-fragments
    v8h pa[4];
#pragma unroll
    for (int ks2 = 0; ks2 < 4; ++ks2) {
      int c = (ks2 << 1) + hi;
      pa[ks2] = *(const v8h*)(pw + (lc << 6) + (((c ^ (lc >> 2)) & 7) << 3));
    }

    // ---- PV: O += P @ V ; l += P @ 1
    __builtin_amdgcn_s_setprio(1);
#pragma unroll
    for (int n = 0; n < 8; ++n) {
#pragma unroll
      for (int ks2 = 0; ks2 < 4; ++ks2) {
        int hd = (n << 5) + lc;
        int c  = (ks2 << 1) + hi;
        v8h vb = *(const v8h*)(sVc + (hd << 6) + (((c ^ (hd >> 2)) & 7) << 3));
        oacc[n] = mfma32h(pa[ks2], vb, oacc[n]);
      }
    }
#pragma unroll
    for (int ks2 = 0; ks2 < 4; ++ks2) accl = mfma32h(pa[ks2], vone, accl);
    __builtin_amdgcn_s_setprio(0);

    __syncthreads();     // next buffer staged (vmcnt drained) & cur free
    cur ^= 1;
  }

  flush(curj);
  if (!hasA) writeEmpty(jA);
  if (!hasB) writeEmpty(jB);
}

// ---------------------------------------------------------------------------
// Kernel 4: merge the 4 chunk-partials per q-row.
// out = sum_i a_i * l_i * Ohat_i / sum_i a_i * l_i,  a_i = exp(m_i - M)
// ---------------------------------------------------------------------------
__global__ __launch_bounds__(256) void merge_kernel(
    const unsigned short* __restrict__ Opart, const float* __restrict__ Mpart,
    const float* __restrict__ Lpart, float* __restrict__ out)
{
  int t = blockIdx.x * 256 + threadIdx.x;     // row*32 + c8
  int row = t >> 5, c8 = t & 31;
  int batch = row >> 12, wi = row & 4095;
  int j = wi >> 7, rloc = wi & 127;
  int sbase = (((batch << 5) + j) << 2);
  float m[4], l[4];
#pragma unroll
  for (int i = 0; i < 4; ++i) {
    m[i] = Mpart[(sbase + i) * 128 + rloc];
    l[i] = Lpart[(sbase + i) * 128 + rloc];
  }
  float M = fmaxf(fmaxf(m[0], m[1]), fmaxf(m[2], m[3]));
  float wgt[4], denom = 0.f;
#pragma unroll
  for (int i = 0; i < 4; ++i) {
    wgt[i] = __expf(m[i] - M) * l[i];
    denom += wgt[i];
  }
  float inv = 1.0f / denom;
  float r8[8] = {};
#pragma unroll
  for (int i = 0; i < 4; ++i) {
    const unsigned short* Op =
        Opart + ((size_t)(sbase + i) * 128 + rloc) * 256 + (c8 << 3);
    v8h v = *(const v8h*)Op;
#pragma unroll
    for (int q = 0; q < 8; ++q) r8[q] += wgt[i] * (float)v[q];
  }
  float* op = out + (size_t)row * 256 + (c8 << 3);
  f32x4 r0, r1;
#pragma unroll
  for (int q = 0; q < 4; ++q) { r0[q] = r8[q] * inv; r1[q] = r8[4 + q] * inv; }
  *(f32x4*)op = r0;
  *(f32x4*)(op + 4) = r1;
}

// ---------------------------------------------------------------------------
extern "C" void kernel_launch(void* const* d_in, const int* in_sizes, int n_in,
                              void* d_out, int out_size, void* d_ws, size_t ws_size,
                              hipStream_t stream) {
  (void)in_sizes; (void)n_in; (void)out_size; (void)ws_size;
  const float* x  = (const float*)d_in[0];
  const float* Wq = (const float*)d_in[1];
  const float* bq = (const float*)d_in[2];
  const float* Wk = (const float*)d_in[3];
  const float* bk = (const float*)d_in[4];
  const float* Wv = (const float*)d_in[5];
  const float* bv = (const float*)d_in[6];
  float* out = (float*)d_out;

  unsigned short* WTh = (unsigned short*)d_ws;          // [3][256][256] bf16
  unsigned short* WTl = WTh + 3 * 65536;
  unsigned short* xh  = WTl + 3 * 65536;                // [16384][256] bf16
  unsigned short* xl  = xh + NROW * HD;
  unsigned short* Qf  = xl + NROW * HD;                 // [16384][256] fp16
  unsigned short* Kf  = Qf + NROW * HD;
  unsigned short* VT  = Kf + NROW * HD;                 // [4][256][4096] fp16
  unsigned short* Opart = VT + (size_t)NB * HD * SEQ;   // [512][128][256] fp16
  float* Mpart = (float*)(Opart + (size_t)512 * 128 * 256);  // [512][128]
  float* Lpart = Mpart + 512 * 128;

  hipLaunchKernelGGL(prep_x_kernel, dim3(2048), dim3(256), 0, stream,
                     x, xh, xl);
  hipLaunchKernelGGL(prep_w_kernel, dim3(768), dim3(256), 0, stream,
                     Wq, Wk, Wv, WTh, WTl);
  hipLaunchKernelGGL(proj_kernel, dim3(256, 3), dim3(256), 0, stream,
                     xh, xl, WTh, WTl, bq, bk, bv, Qf, Kf, VT);
  hipLaunchKernelGGL(attn_kernel, dim3(256), dim3(256), 0, stream,
                     Qf, Kf, VT, Opart, Mpart, Lpart);
  hipLaunchKernelGGL(merge_kernel, dim3(2048), dim3(256), 0, stream,
                     Opart, Mpart, Lpart, out);
}

// Round 7
// 298.743 us; speedup vs baseline: 1.3004x; 1.3004x over previous
//
#include <hip/hip_runtime.h>
#include <stdint.h>

#define HD   256
#define SEQ  4096
#define NB   4
#define NROW (NB * SEQ)   // 16384

typedef __attribute__((ext_vector_type(8))) short short8;
typedef __attribute__((ext_vector_type(4))) float f32x4;
typedef __attribute__((ext_vector_type(16))) float f32x16;
typedef _Float16 v8h __attribute__((ext_vector_type(8)));

__device__ __forceinline__ unsigned short f2bf(float f) {
  union { float f; unsigned u; } v; v.f = f;
  unsigned u = v.u;
  u += 0x7fffu + ((u >> 16) & 1u);
  return (unsigned short)(u >> 16);
}
__device__ __forceinline__ float bf2f(unsigned short h) {
  union { float f; unsigned u; } v; v.u = ((unsigned)h) << 16;
  return v.f;
}
__device__ __forceinline__ unsigned short f2h(float f) {
  union { _Float16 h; unsigned short u; } v;
  v.h = (_Float16)f;
  return v.u;
}

__device__ __forceinline__ f32x4 mfma16(short8 a, short8 b, f32x4 c) {
  return __builtin_amdgcn_mfma_f32_16x16x32_bf16(a, b, c, 0, 0, 0);
}
__device__ __forceinline__ f32x16 mfma32h(v8h a, v8h b, f32x16 c) {
  return __builtin_amdgcn_mfma_f32_32x32x16_f16(a, b, c, 0, 0, 0);
}

__device__ __forceinline__ void gload_lds16(const void* g, void* l) {
  __builtin_amdgcn_global_load_lds((const __attribute__((address_space(1))) void*)g,
                                   (__attribute__((address_space(3))) void*)l,
                                   16, 0, 0);
}

// ---------------------------------------------------------------------------
// Kernel 0: split x (f32) into bf16 hi/lo once.
// ---------------------------------------------------------------------------
__global__ __launch_bounds__(256) void prep_x_kernel(
    const float* __restrict__ x,
    unsigned short* __restrict__ xh, unsigned short* __restrict__ xl)
{
  int i = blockIdx.x * 256 + threadIdx.x;      // 8 elems per thread
  const float* p = x + i * 8;
  f32x4 a0 = *(const f32x4*)p;
  f32x4 a1 = *(const f32x4*)(p + 4);
  short8 hh, ll;
#pragma unroll
  for (int j = 0; j < 4; ++j) {
    unsigned short h0 = f2bf(a0[j]);
    hh[j]     = (short)h0;
    ll[j]     = (short)f2bf(a0[j] - bf2f(h0));
    unsigned short h1 = f2bf(a1[j]);
    hh[4 + j] = (short)h1;
    ll[4 + j] = (short)f2bf(a1[j] - bf2f(h1));
  }
  *(short8*)(xh + i * 8) = hh;
  *(short8*)(xl + i * 8) = ll;
}

// ---------------------------------------------------------------------------
// Kernel 1: transpose + hi/lo split the weight matrices (bf16).
// ---------------------------------------------------------------------------
__global__ __launch_bounds__(256) void prep_w_kernel(
    const float* __restrict__ Wq, const float* __restrict__ Wk,
    const float* __restrict__ Wv,
    unsigned short* __restrict__ WTh, unsigned short* __restrict__ WTl)
{
  int flat = blockIdx.x * 256 + threadIdx.x;   // 0 .. 3*65536-1
  int mat = flat >> 16;
  int e   = flat & 65535;
  int o   = e >> 8;
  int k   = e & 255;
  const float* W = (mat == 0) ? Wq : (mat == 1) ? Wk : Wv;
  float v = W[k * 256 + o];
  unsigned short h = f2bf(v);
  WTh[flat] = h;
  WTl[flat] = f2bf(v - bf2f(h));
}

// ---------------------------------------------------------------------------
// Kernel 2: QKV projection via split-bf16 3-product MFMA; outputs fp16.
// mat 0 -> Qf [row][h], 1 -> Kf [row][h], 2 -> VT [b][h][s] (transposed).
// ---------------------------------------------------------------------------
__global__ __launch_bounds__(256) void proj_kernel(
    const unsigned short* __restrict__ xh, const unsigned short* __restrict__ xl,
    const unsigned short* __restrict__ WTh, const unsigned short* __restrict__ WTl,
    const float* __restrict__ bq, const float* __restrict__ bk,
    const float* __restrict__ bv,
    unsigned short* __restrict__ Qf, unsigned short* __restrict__ Kf,
    unsigned short* __restrict__ VT)
{
  const int mat = blockIdx.y;
  const int r0  = blockIdx.x << 6;     // 64-row tile
  const int tid = threadIdx.x;
  const int w    = tid >> 6;
  const int lane = tid & 63;
  const int lr   = lane & 15;
  const int hi4  = lane >> 4;
  const int r4   = hi4 << 2;

  const unsigned short* wth = WTh + (mat << 16);
  const unsigned short* wtl = WTl + (mat << 16);

  f32x4 acc[4][4] = {};

#pragma unroll
  for (int ks = 0; ks < 8; ++ks) {
    short8 ah[4], al[4];
#pragma unroll
    for (int m = 0; m < 4; ++m) {
      int off = (r0 + (m << 4) + lr) * 256 + (ks << 5) + (hi4 << 3);
      ah[m] = *(const short8*)(xh + off);
      al[m] = *(const short8*)(xl + off);
    }
#pragma unroll
    for (int n = 0; n < 4; ++n) {
      int o = (w << 6) + (n << 4) + lr;
      short8 bh = *(const short8*)(wth + o * 256 + (ks << 5) + (hi4 << 3));
      short8 bl = *(const short8*)(wtl + o * 256 + (ks << 5) + (hi4 << 3));
#pragma unroll
      for (int m = 0; m < 4; ++m) acc[m][n] = mfma16(ah[m], bh, acc[m][n]);
#pragma unroll
      for (int m = 0; m < 4; ++m) acc[m][n] = mfma16(al[m], bh, acc[m][n]);
#pragma unroll
      for (int m = 0; m < 4; ++m) acc[m][n] = mfma16(ah[m], bl, acc[m][n]);
    }
  }

  const float* bias = (mat == 0) ? bq : (mat == 1) ? bk : bv;
#pragma unroll
  for (int n = 0; n < 4; ++n) {
    int col = (w << 6) + (n << 4) + lr;
    float bb = bias[col];
#pragma unroll
    for (int m = 0; m < 4; ++m) {
#pragma unroll
      for (int reg = 0; reg < 4; ++reg) {
        int row = r0 + (m << 4) + r4 + reg;     // global row in [0,16384)
        float val = acc[m][n][reg] + bb;
        unsigned short h = f2h(val);
        if (mat == 0) {
          Qf[row * 256 + col] = h;
        } else if (mat == 1) {
          Kf[row * 256 + col] = h;
        } else {
          int b = row >> 12, s = row & 4095;
          VT[(b << 20) + (col << 12) + s] = h;
        }
      }
    }
  }
}

// ---------------------------------------------------------------------------
// Kernel 3: causal flash attention, 32x32x16 MFMA, BQ=128 (4 waves x 32 rows).
// Same verified grid/pairing/math as round 6; register fix: Q lives in LDS
// (64 KB, staged once per j-segment, XOR-swizzled) and the A-fragment is
// re-read per k-step -> transient regs. Peak ~225 VGPR, no spill.
// LDS: sQ 64K + sK 32K + sV 32K + sP 16K = 144 KB, 1 block/CU,
// single-buffered K/V (stage -> barrier -> compute -> barrier).
// ---------------------------------------------------------------------------
__global__ __launch_bounds__(256, 1) void attn_kernel(
    const unsigned short* __restrict__ Qf, const unsigned short* __restrict__ Kf,
    const unsigned short* __restrict__ VT,
    unsigned short* __restrict__ Opart, float* __restrict__ Mpart,
    float* __restrict__ Lpart)
{
  __shared__ __align__(16) unsigned short sQ[128 * 256];
  __shared__ __align__(16) unsigned short sK[64 * 256];
  __shared__ __align__(16) unsigned short sV[256 * 64];
  __shared__ __align__(16) unsigned short sP[4][32 * 64];

  const int bx    = blockIdx.x;
  const int xcd   = bx & 7;
  const int batch = xcd >> 1;
  const int e     = xcd & 1;
  const int rnk   = bx >> 3;                 // 0..31
  const int p     = rnk & 15;
  const int s     = (rnk >> 4) | (e << 1);   // 0..3
  const int jA = p, jB = 31 - p;
  const int LA = 2 * p + 2;                  // tiles in segment A
  const int g0 = (33 * s) >> 1;              // 0,16,33,49
  const int g1 = (33 * (s + 1)) >> 1;        // 16,33,49,66

  const int tid  = threadIdx.x;
  const int w    = tid >> 6;
  const int lane = tid & 63;
  const int lc   = lane & 31;
  const int hi   = lane >> 5;

  const unsigned short* Kf_b = Kf + (batch << 20);
  const unsigned short* VT_b = VT + (batch << 20);

  auto stageQ = [&](int j) {
    const unsigned short* Qb = Qf + ((size_t)(((batch << 5) + j) * 128) << 8);
#pragma unroll
    for (int it = 0; it < 16; ++it) {
      int id = it * 256 + tid;
      int row = id >> 5, cb = id & 31;
      gload_lds16(Qb + (row << 8) + (((cb ^ (row & 31)) & 31) << 3),
                  sQ + id * 8);
    }
  };

  auto stage = [&](int kt) {
#pragma unroll
    for (int it = 0; it < 8; ++it) {
      int id = it * 256 + tid;
      int kr = id >> 5, cb = id & 31;
      gload_lds16(Kf_b + (((kt << 6) + kr) << 8) + (((cb ^ kr) & 31) << 3),
                  sK + id * 8);
      int hd = id >> 3, cb2 = id & 7;
      gload_lds16(VT_b + (hd << 12) + (kt << 6) + (((cb2 ^ (hd >> 2)) & 7) << 3),
                  sV + id * 8);
    }
  };

  float m_[16];
  f32x16 accl;
  f32x16 oacc[8];
  auto resetAcc = [&]() {
#pragma unroll
    for (int r = 0; r < 16; ++r) { m_[r] = -1e30f; accl[r] = 0.f; }
#pragma unroll
    for (int n = 0; n < 8; ++n)
#pragma unroll
      for (int r = 0; r < 16; ++r) oacc[n][r] = 0.f;
  };

  auto flush = [&](int j) {
    int slot = (((batch << 5) + j) << 2) + s;
    unsigned short* Op = Opart + (size_t)slot * (128 * 256);
    float invl[16];
#pragma unroll
    for (int r = 0; r < 16; ++r)
      invl[r] = (accl[r] > 0.f) ? (1.0f / accl[r]) : 0.f;
#pragma unroll
    for (int n = 0; n < 8; ++n) {
#pragma unroll
      for (int r = 0; r < 16; ++r) {
        int row = (w << 5) + (r & 3) + ((r >> 2) << 3) + (hi << 2);
        Op[row * 256 + (n << 5) + lc] = f2h(oacc[n][r] * invl[r]);
      }
    }
    if (lc == 0) {
#pragma unroll
      for (int r = 0; r < 16; ++r) {
        int row = (w << 5) + (r & 3) + ((r >> 2) << 3) + (hi << 2);
        Mpart[slot * 128 + row] = m_[r];
        Lpart[slot * 128 + row] = accl[r];
      }
    }
  };
  auto writeEmpty = [&](int j) {
    int slot = (((batch << 5) + j) << 2) + s;
    if (lc == 0) {
#pragma unroll
      for (int r = 0; r < 16; ++r) {
        int row = (w << 5) + (r & 3) + ((r >> 2) << 3) + (hi << 2);
        Mpart[slot * 128 + row] = -1e30f;
        Lpart[slot * 128 + row] = 0.f;
      }
    }
  };

  const int aEnd   = (g1 < LA) ? g1 : LA;
  const bool hasA  = g0 < aEnd;
  const int bStart = (g0 > LA) ? g0 : LA;
  const bool hasB  = bStart < g1;

  resetAcc();
  int curj = hasA ? jA : jB;
  stageQ(curj);

  const v8h vone = {(_Float16)1.f, (_Float16)1.f, (_Float16)1.f, (_Float16)1.f,
                    (_Float16)1.f, (_Float16)1.f, (_Float16)1.f, (_Float16)1.f};

  const int qrow   = (w << 5) + lc;                 // this lane's A-row
  const unsigned short* qbase = sQ + (qrow << 8);

  for (int g = g0; g < g1; ++g) {
    const bool inA = g < LA;
    const int j  = inA ? jA : jB;
    const int kt = inA ? g : (g - LA);

    if (j != curj) {           // crossed A->B boundary
      flush(jA);
      resetAcc();
      stageQ(jB);
      curj = jB;
    }

    stage(kt);
    __syncthreads();           // Q (if restaged) + K/V staged, prev reads done

    // ---- QK^T: S[32q][64k], two 32-key column tiles; A=Q from LDS
    f32x16 sacc0, sacc1;
#pragma unroll
    for (int r = 0; r < 16; ++r) { sacc0[r] = 0.f; sacc1[r] = 0.f; }
    __builtin_amdgcn_s_setprio(1);
#pragma unroll
    for (int ks = 0; ks < 16; ++ks) {
      int c = (ks << 1) + hi;                           // 16B chunk index
      v8h qa  = *(const v8h*)(qbase + (((c ^ lc) & 31) << 3));
      v8h kb0 = *(const v8h*)(sK + (lc << 8) + (((c ^ lc) & 31) << 3));
      v8h kb1 = *(const v8h*)(sK + ((32 + lc) << 8) + (((c ^ lc) & 31) << 3));
      sacc0 = mfma32h(qa, kb0, sacc0);
      sacc1 = mfma32h(qa, kb1, sacc1);
    }
    __builtin_amdgcn_s_setprio(0);

    // ---- causal mask (element-wise on diagonal-crossing tiles)
    const int q0 = j << 7;
    if ((kt << 6) + 63 > q0 + (w << 5)) {
#pragma unroll
      for (int r = 0; r < 16; ++r) {
        int qg = q0 + (w << 5) + (r & 3) + ((r >> 2) << 3) + (hi << 2);
        int kg = (kt << 6) + lc;
        if (kg > qg)      sacc0[r] = -3e38f;
        if (kg + 32 > qg) sacc1[r] = -3e38f;
      }
    }

    // ---- row max (reduce over 32 lanes within each half)
    float mx[16];
#pragma unroll
    for (int r = 0; r < 16; ++r) mx[r] = fmaxf(sacc0[r], sacc1[r]);
#pragma unroll
    for (int d = 1; d < 32; d <<= 1) {
#pragma unroll
      for (int r = 0; r < 16; ++r)
        mx[r] = fmaxf(mx[r], __shfl_xor(mx[r], d, 64));
    }

    // ---- defer-max: rescale only when max grows by > 8
    bool need = false;
#pragma unroll
    for (int r = 0; r < 16; ++r) need = need || (mx[r] > m_[r] + 8.0f);
    if (__any(need)) {
#pragma unroll
      for (int r = 0; r < 16; ++r) {
        float mn = fmaxf(m_[r], mx[r]);
        float sc = __expf(m_[r] - mn);
        m_[r] = mn;
        accl[r] *= sc;
#pragma unroll
        for (int n = 0; n < 8; ++n) oacc[n][r] *= sc;
      }
    }

    // ---- P = exp(S - m) -> fp16 -> per-wave swizzled LDS
    unsigned short* pw = (unsigned short*)sP[w];
#pragma unroll
    for (int r = 0; r < 16; ++r) {
      int row = (r & 3) + ((r >> 2) << 3) + (hi << 2);
      int swz = (row >> 2) & 7;
      float p0 = __expf(sacc0[r] - m_[r]);
      float p1 = __expf(sacc1[r] - m_[r]);
      pw[row * 64 + ((((lc >> 3) ^ swz) << 3) | (lc & 7))]        = f2h(p0);
      pw[row * 64 + (((((lc + 32) >> 3) ^ swz) << 3) | (lc & 7))] = f2h(p1);
    }

    // ---- P A-fragments
    v8h pa[4];
#pragma unroll
    for (int ks2 = 0; ks2 < 4; ++ks2) {
      int c = (ks2 << 1) + hi;
      pa[ks2] = *(const v8h*)(pw + (lc << 6) + (((c ^ (lc >> 2)) & 7) << 3));
    }

    // ---- PV: O += P @ V ; l += P @ 1
    __builtin_amdgcn_s_setprio(1);
#pragma unroll
    for (int n = 0; n < 8; ++n) {
#pragma unroll
      for (int ks2 = 0; ks2 < 4; ++ks2) {
        int hd = (n << 5) + lc;
        int c  = (ks2 << 1) + hi;
        v8h vb = *(const v8h*)(sV + (hd << 6) + (((c ^ (hd >> 2)) & 7) << 3));
        oacc[n] = mfma32h(pa[ks2], vb, oacc[n]);
      }
    }
#pragma unroll
    for (int ks2 = 0; ks2 < 4; ++ks2) accl = mfma32h(pa[ks2], vone, accl);
    __builtin_amdgcn_s_setprio(0);

    __syncthreads();           // compute done; buffers free for next stage
  }

  flush(curj);
  if (!hasA) writeEmpty(jA);
  if (!hasB) writeEmpty(jB);
}

// ---------------------------------------------------------------------------
// Kernel 4: merge the 4 chunk-partials per q-row.
// out = sum_i a_i * l_i * Ohat_i / sum_i a_i * l_i,  a_i = exp(m_i - M)
// ---------------------------------------------------------------------------
__global__ __launch_bounds__(256) void merge_kernel(
    const unsigned short* __restrict__ Opart, const float* __restrict__ Mpart,
    const float* __restrict__ Lpart, float* __restrict__ out)
{
  int t = blockIdx.x * 256 + threadIdx.x;     // row*32 + c8
  int row = t >> 5, c8 = t & 31;
  int batch = row >> 12, wi = row & 4095;
  int j = wi >> 7, rloc = wi & 127;
  int sbase = (((batch << 5) + j) << 2);
  float m[4], l[4];
#pragma unroll
  for (int i = 0; i < 4; ++i) {
    m[i] = Mpart[(sbase + i) * 128 + rloc];
    l[i] = Lpart[(sbase + i) * 128 + rloc];
  }
  float M = fmaxf(fmaxf(m[0], m[1]), fmaxf(m[2], m[3]));
  float wgt[4], denom = 0.f;
#pragma unroll
  for (int i = 0; i < 4; ++i) {
    wgt[i] = __expf(m[i] - M) * l[i];
    denom += wgt[i];
  }
  float inv = 1.0f / denom;
  float r8[8] = {};
#pragma unroll
  for (int i = 0; i < 4; ++i) {
    const unsigned short* Op =
        Opart + ((size_t)(sbase + i) * 128 + rloc) * 256 + (c8 << 3);
    v8h v = *(const v8h*)Op;
#pragma unroll
    for (int q = 0; q < 8; ++q) r8[q] += wgt[i] * (float)v[q];
  }
  float* op = out + (size_t)row * 256 + (c8 << 3);
  f32x4 r0, r1;
#pragma unroll
  for (int q = 0; q < 4; ++q) { r0[q] = r8[q] * inv; r1[q] = r8[4 + q] * inv; }
  *(f32x4*)op = r0;
  *(f32x4*)(op + 4) = r1;
}

// ---------------------------------------------------------------------------
extern "C" void kernel_launch(void* const* d_in, const int* in_sizes, int n_in,
                              void* d_out, int out_size, void* d_ws, size_t ws_size,
                              hipStream_t stream) {
  (void)in_sizes; (void)n_in; (void)out_size; (void)ws_size;
  const float* x  = (const float*)d_in[0];
  const float* Wq = (const float*)d_in[1];
  const float* bq = (const float*)d_in[2];
  const float* Wk = (const float*)d_in[3];
  const float* bk = (const float*)d_in[4];
  const float* Wv = (const float*)d_in[5];
  const float* bv = (const float*)d_in[6];
  float* out = (float*)d_out;

  unsigned short* WTh = (unsigned short*)d_ws;          // [3][256][256] bf16
  unsigned short* WTl = WTh + 3 * 65536;
  unsigned short* xh  = WTl + 3 * 65536;                // [16384][256] bf16
  unsigned short* xl  = xh + NROW * HD;
  unsigned short* Qf  = xl + NROW * HD;                 // [16384][256] fp16
  unsigned short* Kf  = Qf + NROW * HD;
  unsigned short* VT  = Kf + NROW * HD;                 // [4][256][4096] fp16
  unsigned short* Opart = VT + (size_t)NB * HD * SEQ;   // [512][128][256] fp16
  float* Mpart = (float*)(Opart + (size_t)512 * 128 * 256);  // [512][128]
  float* Lpart = Mpart + 512 * 128;

  hipLaunchKernelGGL(prep_x_kernel, dim3(2048), dim3(256), 0, stream,
                     x, xh, xl);
  hipLaunchKernelGGL(prep_w_kernel, dim3(768), dim3(256), 0, stream,
                     Wq, Wk, Wv, WTh, WTl);
  hipLaunchKernelGGL(proj_kernel, dim3(256, 3), dim3(256), 0, stream,
                     xh, xl, WTh, WTl, bq, bk, bv, Qf, Kf, VT);
  hipLaunchKernelGGL(attn_kernel, dim3(256), dim3(256), 0, stream,
                     Qf, Kf, VT, Opart, Mpart, Lpart);
  hipLaunchKernelGGL(merge_kernel, dim3(2048), dim3(256), 0, stream,
                     Opart, Mpart, Lpart, out);
}